// Round 7
// baseline (481.515 us; speedup 1.0000x reference)
//
#include <hip/hip_runtime.h>
#include <math.h>

// Problem constants (from setup_inputs)
#define BB   8
#define CXH  16
#define CXL  8
#define HH   256
#define HL   512

// Tiling
#define TS   32              // 512-res tile edge
#define HALO 2
#define GT   (TS + 2*HALO)   // 36 : LN'd tile + halo
#define GP   40              // padded row pitch: f2-stride 20 -> 2-way bank alias only

// Workspace layout:
//  [0, WS_PATCH)            pre-projected xh, branch-pair interleaved
//  [WS_AB_OFF, +16)         folded tail affine A[8], Bc[8]
//  [WS_VB_OFF, +BB*20*HL*HL) per-branch pointwise output v, planar [b][cg][H][W]
#define WS_PATCH_FLOATS (BB * 4 * HH * HH * 2)     // 4,194,304 floats = 16 MB
#define WS_AB_OFF       WS_PATCH_FLOATS
#define WS_VB_OFF       (WS_AB_OFF + 16)
#define WS_VB_FLOATS    ((size_t)BB * 20 * HL * HL)          // 41,943,040 floats
#define WS_SMALL_BYTES  ((size_t)(WS_PATCH_FLOATS + 16) * sizeof(float))
#define WS_BIG_BYTES    (((size_t)WS_PATCH_FLOATS + 16 + WS_VB_FLOATS) * sizeof(float))

// Branch-free fast GELU: x * sigmoid(1.59577x + 0.071355x^3) (tanh-form).
// Max |delta| vs exact erf-GELU ~1e-3 << 0.155 tolerance.
__device__ __forceinline__ float gelu_fast(float x) {
    const float u = x * (1.595769122f + 0.071354816f * x * x);
    return x * __builtin_amdgcn_rcpf(1.0f + __expf(-u));
}

// ---------------- Prepass: 1x1 projection 16 -> 8, pair-interleaved ----------------
__global__ __launch_bounds__(256)
void pre_project_kernel(const float* __restrict__ xh,
                        const float* __restrict__ pre_w,
                        const float* __restrict__ pre_b,
                        const float* __restrict__ tail_ln_w,
                        const float* __restrict__ tail_ln_b,
                        const float* __restrict__ tail_w,
                        const float* __restrict__ tail_b,
                        float* __restrict__ ws)
{
    const int gid = blockIdx.x * 256 + threadIdx.x;   // 524288 = 8*256*256
    const int b   = gid >> 16;
    const int px  = gid & 0xFFFF;                     // iy*256+ix
    const float* xp = xh + (b * CXH) * (HH * HH) + px;
    float xv[16];
    #pragma unroll
    for (int c = 0; c < 16; ++c) xv[c] = xp[c * HH * HH];
    #pragma unroll
    for (int br = 0; br < 4; ++br) {
        float a0 = pre_b[2 * br], a1 = pre_b[2 * br + 1];
        #pragma unroll
        for (int c = 0; c < 16; ++c) {
            a0 += pre_w[(2 * br) * 16 + c] * xv[c];
            a1 += pre_w[(2 * br + 1) * 16 + c] * xv[c];
        }
        float2 r; r.x = a0; r.y = a1;
        *(float2*)&ws[((b * 4 + br) * (HH * HH) + px) * 2] = r;
    }
    if (gid < 8) {
        const int o = gid;
        float a = 0.f, bb = tail_b[o];
        for (int cg = 0; cg < 20; ++cg) {
            a  += tail_w[o * 20 + cg] * tail_ln_w[cg];
            bb += tail_w[o * 20 + cg] * tail_ln_b[cg];
        }
        ws[WS_AB_OFF + o]     = a;
        ws[WS_AB_OFF + 8 + o] = bb;
    }
}

// ---------------- Kernel A: one branch per block ----------------
// grid (16,16,32): blockIdx.z = b*4 + br.  ONE barrier per block; no
// cross-branch accumulators (the R6 fused kernel's 8-barrier chain at 4
// waves/SIMD was the limiter: VALUBusy fell 72->64 with no time change).
__global__ __launch_bounds__(256, 3)
void branch_kernel(const float* __restrict__ xl,
                   const float* __restrict__ mask,
                   const float* __restrict__ g_ln_w,
                   const float* __restrict__ g_ln_b,
                   const float* __restrict__ g_base_w,
                   const float* __restrict__ g_base_b,
                   const float* __restrict__ g_base_s,
                   const float* __restrict__ g_wt_w,
                   const float* __restrict__ g_wt_s,
                   const float* __restrict__ g_pw_w,
                   float* __restrict__ ws)
{
    __shared__ __align__(16) float s_gln[5][GT][GP];   // 28800 B

    const int bz  = blockIdx.z;
    const int b   = bz >> 2;
    const int br  = bz & 3;
    const int ty0 = blockIdx.y * TS;
    const int tx0 = blockIdx.x * TS;
    const int tx  = threadIdx.x, ty = threadIdx.y;
    const int tid = ty * 16 + tx;

    const float SC = (float)(255.0 / 511.0);

    // ---------- Phase 1: build LN'd gi (tile + halo2) in LDS ----------
    const float* wsp = ws + ((size_t)(b * 4 + br) * (HH * HH)) * 2;
    for (int idx = tid; idx < GT * GT; idx += 256) {
        const int ly = idx / GT, lx = idx % GT;
        const int gy = ty0 - HALO + ly, gx = tx0 - HALO + lx;
        float vv[5] = {0.f, 0.f, 0.f, 0.f, 0.f};
        if (gy >= 0 && gy < HL && gx >= 0 && gx < HL) {
            const float cy = (float)gy * SC;
            const int iy0 = min((int)cy, HH - 2);
            const float fy = cy - (float)iy0;
            const float cx = (float)gx * SC;
            const int ix0 = min((int)cx, HH - 2);
            const float fx = cx - (float)ix0;
            const float2 q00 = *(const float2*)&wsp[(iy0 * HH + ix0) * 2];
            const float2 q01 = *(const float2*)&wsp[(iy0 * HH + ix0 + 1) * 2];
            const float2 q10 = *(const float2*)&wsp[((iy0 + 1) * HH + ix0) * 2];
            const float2 q11 = *(const float2*)&wsp[((iy0 + 1) * HH + ix0 + 1) * 2];
            {
                const float top = q00.x + fx * (q01.x - q00.x);
                const float bot = q10.x + fx * (q11.x - q10.x);
                vv[0] = top + fy * (bot - top);
            }
            {
                const float top = q00.y + fx * (q01.y - q00.y);
                const float bot = q10.y + fx * (q11.y - q10.y);
                vv[1] = top + fy * (bot - top);
            }
            const int xbase = ((b * CXL) * HL + gy) * HL + gx;
            vv[2] = xl[xbase + (2 * br) * HL * HL];
            vv[3] = xl[xbase + (2 * br + 1) * HL * HL];
            vv[4] = mask[(b * HL + gy) * HL + gx];
            const float u = (vv[0] + vv[1] + vv[2] + vv[3] + vv[4]) * 0.2f;
            float var = 0.f;
            #pragma unroll
            for (int c = 0; c < 5; ++c) { const float d = vv[c] - u; var += d * d; }
            var *= 0.2f;
            const float rstd = rsqrtf(var + 1e-6f);
            #pragma unroll
            for (int c = 0; c < 5; ++c)
                vv[c] = g_ln_w[br * 5 + c] * ((vv[c] - u) * rstd) + g_ln_b[br * 5 + c];
        }
        #pragma unroll
        for (int c = 0; c < 5; ++c) s_gln[c][ly][lx] = vv[c];
    }
    __syncthreads();

    // ---------- Register DWT + subband dwconv + IDWT + base conv ----------
    const float* wb = g_wt_w + br * 180;
    float gi[5][4];
    #pragma unroll
    for (int c = 0; c < 5; ++c) {
        float P[6][6];
        #pragma unroll
        for (int r = 0; r < 6; ++r) {
            const float* rp = &s_gln[c][2 * ty + r][2 * tx];
            const float2 pa = *(const float2*)(rp);
            const float2 pb = *(const float2*)(rp + 2);
            const float2 pc = *(const float2*)(rp + 4);
            P[r][0] = pa.x; P[r][1] = pa.y;
            P[r][2] = pb.x; P[r][3] = pb.y;
            P[r][4] = pc.x; P[r][5] = pc.y;
        }
        float tc0 = 0.f, tc1 = 0.f, tc2 = 0.f, tc3 = 0.f;
        #pragma unroll
        for (int dy = 0; dy < 3; ++dy) {
            #pragma unroll
            for (int dx = 0; dx < 3; ++dx) {
                const float a  = P[2 * dy][2 * dx];
                const float b2 = P[2 * dy][2 * dx + 1];
                const float c2 = P[2 * dy + 1][2 * dx];
                const float d2 = P[2 * dy + 1][2 * dx + 1];
                const float s0 = a + b2, s1 = c2 + d2;
                const float d0 = a - b2, d1 = c2 - d2;
                const int wo = dy * 3 + dx;
                tc0 += wb[(c * 4 + 0) * 9 + wo] * (s0 + s1);   // 2*LL
                tc1 += wb[(c * 4 + 1) * 9 + wo] * (s0 - s1);   // 2*LH
                tc2 += wb[(c * 4 + 2) * 9 + wo] * (d0 + d1);   // 2*HL
                tc3 += wb[(c * 4 + 3) * 9 + wo] * (d0 - d1);   // 2*HH
            }
        }
        const float t0 = tc0 * (0.5f * g_wt_s[br * 20 + c * 4 + 0]);
        const float t1 = tc1 * (0.5f * g_wt_s[br * 20 + c * 4 + 1]);
        const float t2 = tc2 * (0.5f * g_wt_s[br * 20 + c * 4 + 2]);
        const float t3 = tc3 * (0.5f * g_wt_s[br * 20 + c * 4 + 3]);
        const float xt0 = 0.5f * (t0 + t1 + t2 + t3);
        const float xt1 = 0.5f * (t0 + t1 - t2 - t3);
        const float xt2 = 0.5f * (t0 - t1 + t2 - t3);
        const float xt3 = 0.5f * (t0 - t1 - t2 + t3);
        const float* bw = g_base_w + br * 45 + c * 9;
        const float bb2 = g_base_b[br * 5 + c], bs = g_base_s[br * 5 + c];
        #pragma unroll
        for (int p = 0; p < 4; ++p) {
            const int py = p >> 1, px = p & 1;
            float acc = 0.f;
            #pragma unroll
            for (int dy = 0; dy < 3; ++dy)
                #pragma unroll
                for (int dx = 0; dx < 3; ++dx)
                    acc += bw[dy * 3 + dx] * P[1 + py + dy][1 + px + dx];
            const float xtv = (p == 0) ? xt0 : (p == 1) ? xt1 : (p == 2) ? xt2 : xt3;
            gi[c][p] = (acc + bb2) * bs + xtv;
        }
    }

    // ---------- 5x5 pointwise -> stream v channels to workspace ----------
    const size_t vplane = (size_t)HL * HL;
    float* vb = ws + WS_VB_OFF + (size_t)(b * 20 + br * 5) * vplane;
    const int gy0 = ty0 + 2 * ty;
    const int gx0 = tx0 + 2 * tx;
    #pragma unroll
    for (int o = 0; o < 5; ++o) {
        float v[4];
        #pragma unroll
        for (int p = 0; p < 4; ++p) {
            float vv = 0.f;
            #pragma unroll
            for (int c = 0; c < 5; ++c) vv += g_pw_w[br * 25 + o * 5 + c] * gi[c][p];
            v[p] = vv;
        }
        float* op = vb + o * vplane + gy0 * HL + gx0;
        float2 r0; r0.x = v[0]; r0.y = v[1];
        float2 r1; r1.x = v[2]; r1.y = v[3];
        *(float2*)(op)      = r0;
        *(float2*)(op + HL) = r1;
    }
}

// ---------------- Kernel B: tail LN + 1x1 + GELU + residual (streaming) ----------------
__global__ __launch_bounds__(256)
void tail_kernel(const float* __restrict__ xl,
                 const float* __restrict__ mask,
                 const float* __restrict__ tail_ln_w,
                 const float* __restrict__ tail_w,
                 const float* __restrict__ res_w,
                 const float* __restrict__ res_b,
                 const float* __restrict__ ws,
                 float* __restrict__ out)
{
    const int gid = blockIdx.x * 256 + threadIdx.x;   // 2,097,152 = 8*512*512
    const int b   = gid >> 18;
    const int pix = gid & 0x3FFFF;                    // gy*512+gx
    const size_t vplane = (size_t)HL * HL;

    const float* vb = ws + WS_VB_OFF + (size_t)b * 20 * vplane + pix;
    float vw[20];
    float s = 0.f;
    #pragma unroll
    for (int cg = 0; cg < 20; ++cg) {
        const float v = vb[cg * vplane];
        vw[cg] = v;
        s += v;
    }
    const float u = s * 0.05f;
    float var = 0.f;
    #pragma unroll
    for (int cg = 0; cg < 20; ++cg) { const float d = vw[cg] - u; var += d * d; }
    const float rstd = rsqrtf(var * 0.05f + 1e-6f);
    // scale by tail LN weight once (folded-affine form: val = (t - u*A)*rstd + Bc)
    #pragma unroll
    for (int cg = 0; cg < 20; ++cg) vw[cg] *= tail_ln_w[cg];

    const float* xp = xl + (size_t)(b * CXL) * vplane + pix;
    float xlv[8];
    #pragma unroll
    for (int c = 0; c < 8; ++c) xlv[c] = xp[c * vplane];
    const float mk = mask[(size_t)b * vplane + pix];

    float* op = out + (size_t)(b * CXL) * vplane + pix;
    #pragma unroll
    for (int o = 0; o < 8; ++o) {
        float t = 0.f;
        #pragma unroll
        for (int cg = 0; cg < 20; ++cg) t += tail_w[o * 20 + cg] * vw[cg];
        const float val = (t - u * ws[WS_AB_OFF + o]) * rstd + ws[WS_AB_OFF + 8 + o];
        float r = res_b[o] + res_w[o * 9 + 8] * mk;
        #pragma unroll
        for (int c = 0; c < 8; ++c) r += res_w[o * 9 + c] * xlv[c];
        op[o * vplane] = gelu_fast(val) + r;
    }
}

// ---------------- Fallback: R6 fused kernel (small / absent workspace) ----------------
template <bool USE_WS>
__global__ __launch_bounds__(256, 3)
void uem_fused_kernel(const float* __restrict__ xh,
                      const float* __restrict__ xl,
                      const float* __restrict__ mask,
                      const float* __restrict__ pre_w,
                      const float* __restrict__ pre_b,
                      const float* __restrict__ g_ln_w,
                      const float* __restrict__ g_ln_b,
                      const float* __restrict__ g_base_w,
                      const float* __restrict__ g_base_b,
                      const float* __restrict__ g_base_s,
                      const float* __restrict__ g_wt_w,
                      const float* __restrict__ g_wt_s,
                      const float* __restrict__ g_pw_w,
                      const float* __restrict__ tail_ln_w,
                      const float* __restrict__ tail_ln_b,
                      const float* __restrict__ tail_w,
                      const float* __restrict__ tail_b,
                      const float* __restrict__ res_w,
                      const float* __restrict__ res_b,
                      const float* __restrict__ ws,
                      float* __restrict__ out)
{
    __shared__ __align__(16) float s_gln[5][GT][GP];

    const int b   = blockIdx.z;
    const int ty0 = blockIdx.y * TS;
    const int tx0 = blockIdx.x * TS;
    const int tx  = threadIdx.x, ty = threadIdx.y;
    const int tid = ty * 16 + tx;

    const float SC = (float)(255.0 / 511.0);

    float S1[4] = {0.f, 0.f, 0.f, 0.f};
    float S2[4] = {0.f, 0.f, 0.f, 0.f};
    float T[4][8];
    #pragma unroll
    for (int p = 0; p < 4; ++p)
        #pragma unroll
        for (int o = 0; o < 8; ++o) T[p][o] = 0.f;

    for (int br = 0; br < 4; ++br) {
        for (int idx = tid; idx < GT * GT; idx += 256) {
            const int ly = idx / GT, lx = idx % GT;
            const int gy = ty0 - HALO + ly, gx = tx0 - HALO + lx;
            float vv[5] = {0.f, 0.f, 0.f, 0.f, 0.f};
            if (gy >= 0 && gy < HL && gx >= 0 && gx < HL) {
                const float cy = (float)gy * SC;
                const int iy0 = min((int)cy, HH - 2);
                const float fy = cy - (float)iy0;
                const float cx = (float)gx * SC;
                const int ix0 = min((int)cx, HH - 2);
                const float fx = cx - (float)ix0;
                float2 q00, q01, q10, q11;
                if (USE_WS) {
                    const float* wsp = ws + ((size_t)(b * 4 + br) * (HH * HH)) * 2;
                    q00 = *(const float2*)&wsp[(iy0 * HH + ix0) * 2];
                    q01 = *(const float2*)&wsp[(iy0 * HH + ix0 + 1) * 2];
                    q10 = *(const float2*)&wsp[((iy0 + 1) * HH + ix0) * 2];
                    q11 = *(const float2*)&wsp[((iy0 + 1) * HH + ix0 + 1) * 2];
                } else {
                    #pragma unroll
                    for (int q = 0; q < 4; ++q) {
                        const int iy = iy0 + (q >> 1), ix = ix0 + (q & 1);
                        const float* xp = xh + ((b * CXH) * HH + iy) * HH + ix;
                        float a0 = pre_b[2 * br], a1 = pre_b[2 * br + 1];
                        #pragma unroll
                        for (int c = 0; c < 16; ++c) {
                            const float v = xp[c * HH * HH];
                            a0 += pre_w[(2 * br) * 16 + c] * v;
                            a1 += pre_w[(2 * br + 1) * 16 + c] * v;
                        }
                        float2 r; r.x = a0; r.y = a1;
                        if (q == 0) q00 = r; else if (q == 1) q01 = r;
                        else if (q == 2) q10 = r; else q11 = r;
                    }
                }
                {
                    const float top = q00.x + fx * (q01.x - q00.x);
                    const float bot = q10.x + fx * (q11.x - q10.x);
                    vv[0] = top + fy * (bot - top);
                }
                {
                    const float top = q00.y + fx * (q01.y - q00.y);
                    const float bot = q10.y + fx * (q11.y - q10.y);
                    vv[1] = top + fy * (bot - top);
                }
                const int xbase = ((b * CXL) * HL + gy) * HL + gx;
                vv[2] = xl[xbase + (2 * br) * HL * HL];
                vv[3] = xl[xbase + (2 * br + 1) * HL * HL];
                vv[4] = mask[(b * HL + gy) * HL + gx];
                const float u = (vv[0] + vv[1] + vv[2] + vv[3] + vv[4]) * 0.2f;
                float var = 0.f;
                #pragma unroll
                for (int c = 0; c < 5; ++c) { const float d = vv[c] - u; var += d * d; }
                var *= 0.2f;
                const float rstd = rsqrtf(var + 1e-6f);
                #pragma unroll
                for (int c = 0; c < 5; ++c)
                    vv[c] = g_ln_w[br * 5 + c] * ((vv[c] - u) * rstd) + g_ln_b[br * 5 + c];
            }
            #pragma unroll
            for (int c = 0; c < 5; ++c) s_gln[c][ly][lx] = vv[c];
        }
        __syncthreads();

        const float* wb = g_wt_w + br * 180;
        float gi[5][4];
        #pragma unroll
        for (int c = 0; c < 5; ++c) {
            float P[6][6];
            #pragma unroll
            for (int r = 0; r < 6; ++r) {
                const float* rp = &s_gln[c][2 * ty + r][2 * tx];
                const float2 pa = *(const float2*)(rp);
                const float2 pb = *(const float2*)(rp + 2);
                const float2 pc = *(const float2*)(rp + 4);
                P[r][0] = pa.x; P[r][1] = pa.y;
                P[r][2] = pb.x; P[r][3] = pb.y;
                P[r][4] = pc.x; P[r][5] = pc.y;
            }
            float tc0 = 0.f, tc1 = 0.f, tc2 = 0.f, tc3 = 0.f;
            #pragma unroll
            for (int dy = 0; dy < 3; ++dy) {
                #pragma unroll
                for (int dx = 0; dx < 3; ++dx) {
                    const float a  = P[2 * dy][2 * dx];
                    const float b2 = P[2 * dy][2 * dx + 1];
                    const float c2 = P[2 * dy + 1][2 * dx];
                    const float d2 = P[2 * dy + 1][2 * dx + 1];
                    const float s0 = a + b2, s1 = c2 + d2;
                    const float d0 = a - b2, d1 = c2 - d2;
                    const int wo = dy * 3 + dx;
                    tc0 += wb[(c * 4 + 0) * 9 + wo] * (s0 + s1);
                    tc1 += wb[(c * 4 + 1) * 9 + wo] * (s0 - s1);
                    tc2 += wb[(c * 4 + 2) * 9 + wo] * (d0 + d1);
                    tc3 += wb[(c * 4 + 3) * 9 + wo] * (d0 - d1);
                }
            }
            const float t0 = tc0 * (0.5f * g_wt_s[br * 20 + c * 4 + 0]);
            const float t1 = tc1 * (0.5f * g_wt_s[br * 20 + c * 4 + 1]);
            const float t2 = tc2 * (0.5f * g_wt_s[br * 20 + c * 4 + 2]);
            const float t3 = tc3 * (0.5f * g_wt_s[br * 20 + c * 4 + 3]);
            const float xt0 = 0.5f * (t0 + t1 + t2 + t3);
            const float xt1 = 0.5f * (t0 + t1 - t2 - t3);
            const float xt2 = 0.5f * (t0 - t1 + t2 - t3);
            const float xt3 = 0.5f * (t0 - t1 - t2 + t3);
            const float* bw = g_base_w + br * 45 + c * 9;
            const float bb2 = g_base_b[br * 5 + c], bs = g_base_s[br * 5 + c];
            #pragma unroll
            for (int p = 0; p < 4; ++p) {
                const int py = p >> 1, px = p & 1;
                float acc = 0.f;
                #pragma unroll
                for (int dy = 0; dy < 3; ++dy)
                    #pragma unroll
                    for (int dx = 0; dx < 3; ++dx)
                        acc += bw[dy * 3 + dx] * P[1 + py + dy][1 + px + dx];
                const float xtv = (p == 0) ? xt0 : (p == 1) ? xt1 : (p == 2) ? xt2 : xt3;
                gi[c][p] = (acc + bb2) * bs + xtv;
            }
        }

        #pragma unroll
        for (int o = 0; o < 5; ++o) {
            const int cg = br * 5 + o;
            float v[4];
            #pragma unroll
            for (int p = 0; p < 4; ++p) {
                float vv = 0.f;
                #pragma unroll
                for (int c = 0; c < 5; ++c) vv += g_pw_w[br * 25 + o * 5 + c] * gi[c][p];
                v[p] = vv;
                S1[p] += vv;
                S2[p] += vv * vv;
            }
            const float lw = tail_ln_w[cg];
            #pragma unroll
            for (int o8 = 0; o8 < 8; ++o8) {
                const float w = tail_w[o8 * 20 + cg] * lw;
                T[0][o8] += w * v[0];
                T[1][o8] += w * v[1];
                T[2][o8] += w * v[2];
                T[3][o8] += w * v[3];
            }
        }
        __syncthreads();
    }

    float A[8], Bc[8];
    if (USE_WS) {
        #pragma unroll
        for (int o = 0; o < 8; ++o) {
            A[o]  = ws[WS_AB_OFF + o];
            Bc[o] = ws[WS_AB_OFF + 8 + o];
        }
    } else {
        #pragma unroll
        for (int o = 0; o < 8; ++o) {
            float a = 0.f, bb = tail_b[o];
            #pragma unroll
            for (int cg = 0; cg < 20; ++cg) {
                a  += tail_w[o * 20 + cg] * tail_ln_w[cg];
                bb += tail_w[o * 20 + cg] * tail_ln_b[cg];
            }
            A[o] = a; Bc[o] = bb;
        }
    }

    #pragma unroll
    for (int py = 0; py < 2; ++py) {
        const int p0 = py * 2, p1 = py * 2 + 1;
        const int gy  = ty0 + 2 * ty + py;
        const int gx0 = tx0 + 2 * tx;
        const float u0    = S1[p0] * 0.05f;
        const float u1    = S1[p1] * 0.05f;
        const float rstd0 = rsqrtf(S2[p0] * 0.05f - u0 * u0 + 1e-6f);
        const float rstd1 = rsqrtf(S2[p1] * 0.05f - u1 * u1 + 1e-6f);

        const int xbase = ((b * CXL) * HL + gy) * HL + gx0;
        float2 xlv[8];
        #pragma unroll
        for (int c = 0; c < 8; ++c) xlv[c] = *(const float2*)&xl[xbase + c * HL * HL];
        const float2 mk = *(const float2*)&mask[(b * HL + gy) * HL + gx0];

        #pragma unroll
        for (int o = 0; o < 8; ++o) {
            const float val0 = (T[p0][o] - u0 * A[o]) * rstd0 + Bc[o];
            const float val1 = (T[p1][o] - u1 * A[o]) * rstd1 + Bc[o];
            float r0 = res_b[o] + res_w[o * 9 + 8] * mk.x;
            float r1 = res_b[o] + res_w[o * 9 + 8] * mk.y;
            #pragma unroll
            for (int c = 0; c < 8; ++c) {
                r0 += res_w[o * 9 + c] * xlv[c].x;
                r1 += res_w[o * 9 + c] * xlv[c].y;
            }
            float2 ov;
            ov.x = gelu_fast(val0) + r0;
            ov.y = gelu_fast(val1) + r1;
            *(float2*)&out[xbase + o * HL * HL] = ov;
        }
    }
}

extern "C" void kernel_launch(void* const* d_in, const int* in_sizes, int n_in,
                              void* d_out, int out_size, void* d_ws, size_t ws_size,
                              hipStream_t stream) {
    (void)in_sizes; (void)out_size;
    if (n_in < 19) return;
    const float* xh        = (const float*)d_in[0];
    const float* xl        = (const float*)d_in[1];
    const float* mask      = (const float*)d_in[2];
    const float* pre_w     = (const float*)d_in[3];
    const float* pre_b     = (const float*)d_in[4];
    const float* g_ln_w    = (const float*)d_in[5];
    const float* g_ln_b    = (const float*)d_in[6];
    const float* g_base_w  = (const float*)d_in[7];
    const float* g_base_b  = (const float*)d_in[8];
    const float* g_base_s  = (const float*)d_in[9];
    const float* g_wt_w    = (const float*)d_in[10];
    const float* g_wt_s    = (const float*)d_in[11];
    const float* g_pw_w    = (const float*)d_in[12];
    const float* tail_ln_w = (const float*)d_in[13];
    const float* tail_ln_b = (const float*)d_in[14];
    const float* tail_w    = (const float*)d_in[15];
    const float* tail_b    = (const float*)d_in[16];
    const float* res_w     = (const float*)d_in[17];
    const float* res_b     = (const float*)d_in[18];
    float* outp = (float*)d_out;
    float* ws   = (float*)d_ws;

    dim3 block(16, 16, 1);

    if (ws != nullptr && ws_size >= WS_BIG_BYTES) {
        pre_project_kernel<<<dim3(2048), dim3(256), 0, stream>>>(
            xh, pre_w, pre_b, tail_ln_w, tail_ln_b, tail_w, tail_b, ws);
        branch_kernel<<<dim3(HL / TS, HL / TS, BB * 4), block, 0, stream>>>(
            xl, mask, g_ln_w, g_ln_b, g_base_w, g_base_b, g_base_s,
            g_wt_w, g_wt_s, g_pw_w, ws);
        tail_kernel<<<dim3(BB * HL * HL / 256), dim3(256), 0, stream>>>(
            xl, mask, tail_ln_w, tail_w, res_w, res_b, ws, outp);
    } else if (ws != nullptr && ws_size >= WS_SMALL_BYTES) {
        pre_project_kernel<<<dim3(2048), dim3(256), 0, stream>>>(
            xh, pre_w, pre_b, tail_ln_w, tail_ln_b, tail_w, tail_b, ws);
        uem_fused_kernel<true><<<dim3(HL / TS, HL / TS, BB), block, 0, stream>>>(
            xh, xl, mask, pre_w, pre_b, g_ln_w, g_ln_b, g_base_w, g_base_b,
            g_base_s, g_wt_w, g_wt_s, g_pw_w, tail_ln_w, tail_ln_b, tail_w,
            tail_b, res_w, res_b, ws, outp);
    } else {
        uem_fused_kernel<false><<<dim3(HL / TS, HL / TS, BB), block, 0, stream>>>(
            xh, xl, mask, pre_w, pre_b, g_ln_w, g_ln_b, g_base_w, g_base_b,
            g_base_s, g_wt_w, g_wt_s, g_pw_w, tail_ln_w, tail_ln_b, tail_w,
            tail_b, res_w, res_b, ws, outp);
    }
}

// Round 9
// 296.600 us; speedup vs baseline: 1.6234x; 1.6234x over previous
//
#include <hip/hip_runtime.h>
#include <math.h>

// Problem constants (from setup_inputs)
#define BB   8
#define CXH  16
#define CXL  8
#define HH   256
#define HL   512

// Tiling
#define TS   32              // 512-res tile edge
#define HALO 2
#define GT   (TS + 2*HALO)   // 36 : LN'd tile + halo
#define NPX  (GT * GT)       // 1296 halo'd pixels per tile

// Workspace: pre-projected xh (pair-interleaved) + folded tail affine
#define WS_PATCH_FLOATS (BB * 4 * HH * HH * 2)     // 16 MB
#define WS_AB_OFF       WS_PATCH_FLOATS
#define WS_NEEDED_BYTES ((size_t)(WS_PATCH_FLOATS + 16) * sizeof(float))

// Branch-free fast GELU (tanh-form); |delta| vs exact ~1e-3 << 0.155 tol.
__device__ __forceinline__ float gelu_fast(float x) {
    const float u = x * (1.595769122f + 0.071354816f * x * x);
    return x * __builtin_amdgcn_rcpf(1.0f + __expf(-u));
}

// Channels-first LN over 5 values (order identical to all prior rounds).
__device__ __forceinline__ void ln5(float* vv, const float* w, const float* bta) {
    const float u = (vv[0] + vv[1] + vv[2] + vv[3] + vv[4]) * 0.2f;
    float var = 0.f;
    #pragma unroll
    for (int c = 0; c < 5; ++c) { const float d = vv[c] - u; var += d * d; }
    var *= 0.2f;
    const float rstd = rsqrtf(var + 1e-6f);
    #pragma unroll
    for (int c = 0; c < 5; ++c) vv[c] = w[c] * ((vv[c] - u) * rstd) + bta[c];
}

// ---------------- Prepass: 1x1 projection 16 -> 8, pair-interleaved ----------------
__global__ __launch_bounds__(256)
void pre_project_kernel(const float* __restrict__ xh,
                        const float* __restrict__ pre_w,
                        const float* __restrict__ pre_b,
                        const float* __restrict__ tail_ln_w,
                        const float* __restrict__ tail_ln_b,
                        const float* __restrict__ tail_w,
                        const float* __restrict__ tail_b,
                        float* __restrict__ ws)
{
    const int gid = blockIdx.x * 256 + threadIdx.x;   // 524288 = 8*256*256
    const int b   = gid >> 16;
    const int px  = gid & 0xFFFF;
    const float* xp = xh + (b * CXH) * (HH * HH) + px;
    float xv[16];
    #pragma unroll
    for (int c = 0; c < 16; ++c) xv[c] = xp[c * HH * HH];
    #pragma unroll
    for (int br = 0; br < 4; ++br) {
        float a0 = pre_b[2 * br], a1 = pre_b[2 * br + 1];
        #pragma unroll
        for (int c = 0; c < 16; ++c) {
            a0 += pre_w[(2 * br) * 16 + c] * xv[c];
            a1 += pre_w[(2 * br + 1) * 16 + c] * xv[c];
        }
        float2 r; r.x = a0; r.y = a1;
        *(float2*)&ws[((b * 4 + br) * (HH * HH) + px) * 2] = r;
    }
    if (gid < 8) {
        const int o = gid;
        float a = 0.f, bb = tail_b[o];
        for (int cg = 0; cg < 20; ++cg) {
            a  += tail_w[o * 20 + cg] * tail_ln_w[cg];
            bb += tail_w[o * 20 + cg] * tail_ln_b[cg];
        }
        ws[WS_AB_OFF + o]     = a;
        ws[WS_AB_OFF + 8 + o] = bb;
    }
}

// ---------------- Main fused kernel: branch-PAIR loop ----------------
// R6 structure with three contained changes (R7 split reverted):
//  * 2 branches resident in LDS per pass: branch-invariant bilinear coeffs /
//    bounds / addressing / mask computed once per PAIR; barriers 8 -> 3.
//  * quad-interleaved LDS [slot][ch][qy][qx][2x2]: conv patch = 9
//    ds_read_b128 per channel (was 18 b64), 16B-aligned, <=2-way bank alias.
//  * incremental ly/lx (no div/mod by 36 in the phase-1 loop).
// LDS 51840 B -> 3 blocks/CU (measured occupancy was ~30% at 3 AND 4
// blocks/CU across R1..R6, so the 4->3 cap costs nothing observable).
__global__ __launch_bounds__(256, 3)
void uem_pair_kernel(const float* __restrict__ xl,
                     const float* __restrict__ mask,
                     const float* __restrict__ g_ln_w,
                     const float* __restrict__ g_ln_b,
                     const float* __restrict__ g_base_w,
                     const float* __restrict__ g_base_b,
                     const float* __restrict__ g_base_s,
                     const float* __restrict__ g_wt_w,
                     const float* __restrict__ g_wt_s,
                     const float* __restrict__ g_pw_w,
                     const float* __restrict__ tail_ln_w,
                     const float* __restrict__ tail_w,
                     const float* __restrict__ res_w,
                     const float* __restrict__ res_b,
                     const float* __restrict__ ws,
                     float* __restrict__ out)
{
    __shared__ __align__(16) float s_q[2][5][18][18][4];   // 51840 B

    const int b   = blockIdx.z;
    const int ty0 = blockIdx.y * TS;
    const int tx0 = blockIdx.x * TS;
    const int tx  = threadIdx.x, ty = threadIdx.y;
    const int tid = ty * 16 + tx;

    const float SC = (float)(255.0 / 511.0);   // align_corners scale
    const int plane = HL * HL;
    const int mb  = b * plane;
    const int xlb = (b * CXL) * plane;

    float S1[4] = {0.f, 0.f, 0.f, 0.f};
    float S2[4] = {0.f, 0.f, 0.f, 0.f};
    float T[4][8];
    #pragma unroll
    for (int p = 0; p < 4; ++p)
        #pragma unroll
        for (int o = 0; o < 8; ++o) T[p][o] = 0.f;

    for (int pair = 0; pair < 2; ++pair) {
        // ---------- Phase 1: LN'd inputs for BOTH branches of the pair ----------
        const float* wsp0 = ws + ((size_t)(b * 4 + 2 * pair)     * (HH * HH)) * 2;
        const float* wsp1 = ws + ((size_t)(b * 4 + 2 * pair + 1) * (HH * HH)) * 2;
        int ly = tid / 36, lx = tid % 36;
        for (int idx = tid; idx < NPX; idx += 256) {
            const int gy = ty0 - HALO + ly, gx = tx0 - HALO + lx;
            float va[5] = {0.f, 0.f, 0.f, 0.f, 0.f};
            float vb[5] = {0.f, 0.f, 0.f, 0.f, 0.f};
            if (gy >= 0 && gy < HL && gx >= 0 && gx < HL) {
                // branch-invariant coefficients (computed once per pair)
                const float cy = (float)gy * SC;
                const int iy0 = min((int)cy, HH - 2);
                const float fy = cy - (float)iy0;
                const float cx = (float)gx * SC;
                const int ix0 = min((int)cx, HH - 2);
                const float fx = cx - (float)ix0;
                const int co  = (iy0 * HH + ix0) * 2;
                const int pix = gy * HL + gx;
                const float mk = mask[mb + pix];
                // branch A (2*pair)
                {
                    const float2 q00 = *(const float2*)&wsp0[co];
                    const float2 q01 = *(const float2*)&wsp0[co + 2];
                    const float2 q10 = *(const float2*)&wsp0[co + 2 * HH];
                    const float2 q11 = *(const float2*)&wsp0[co + 2 * HH + 2];
                    {
                        const float top = q00.x + fx * (q01.x - q00.x);
                        const float bot = q10.x + fx * (q11.x - q10.x);
                        va[0] = top + fy * (bot - top);
                    }
                    {
                        const float top = q00.y + fx * (q01.y - q00.y);
                        const float bot = q10.y + fx * (q11.y - q10.y);
                        va[1] = top + fy * (bot - top);
                    }
                    va[2] = xl[xlb + (4 * pair + 0) * plane + pix];
                    va[3] = xl[xlb + (4 * pair + 1) * plane + pix];
                    va[4] = mk;
                    ln5(va, g_ln_w + (2 * pair) * 5, g_ln_b + (2 * pair) * 5);
                }
                // branch B (2*pair+1)
                {
                    const float2 q00 = *(const float2*)&wsp1[co];
                    const float2 q01 = *(const float2*)&wsp1[co + 2];
                    const float2 q10 = *(const float2*)&wsp1[co + 2 * HH];
                    const float2 q11 = *(const float2*)&wsp1[co + 2 * HH + 2];
                    {
                        const float top = q00.x + fx * (q01.x - q00.x);
                        const float bot = q10.x + fx * (q11.x - q10.x);
                        vb[0] = top + fy * (bot - top);
                    }
                    {
                        const float top = q00.y + fx * (q01.y - q00.y);
                        const float bot = q10.y + fx * (q11.y - q10.y);
                        vb[1] = top + fy * (bot - top);
                    }
                    vb[2] = xl[xlb + (4 * pair + 2) * plane + pix];
                    vb[3] = xl[xlb + (4 * pair + 3) * plane + pix];
                    vb[4] = mk;
                    ln5(vb, g_ln_w + (2 * pair + 1) * 5, g_ln_b + (2 * pair + 1) * 5);
                }
            }
            const int qy = ly >> 1, qx = lx >> 1, sub = (ly & 1) * 2 + (lx & 1);
            #pragma unroll
            for (int c = 0; c < 5; ++c) s_q[0][c][qy][qx][sub] = va[c];
            #pragma unroll
            for (int c = 0; c < 5; ++c) s_q[1][c][qy][qx][sub] = vb[c];
            // idx += 256  ==  ly += 7, lx += 4  (256 = 7*36 + 4), single wrap
            lx += 4; ly += 7;
            if (lx >= 36) { lx -= 36; ly += 1; }
        }
        __syncthreads();

        // ---------- Conv block for each branch of the pair ----------
        for (int s = 0; s < 2; ++s) {
            const int br = 2 * pair + s;
            const float* wb = g_wt_w + br * 180;
            float gi[5][4];
            #pragma unroll
            for (int c = 0; c < 5; ++c) {
                // 6x6 patch via 9 aligned b128 quad reads
                float P[6][6];
                #pragma unroll
                for (int a = 0; a < 3; ++a)
                    #pragma unroll
                    for (int bq = 0; bq < 3; ++bq) {
                        const float4 q = *(const float4*)&s_q[s][c][ty + a][tx + bq][0];
                        P[2 * a][2 * bq]         = q.x;
                        P[2 * a][2 * bq + 1]     = q.y;
                        P[2 * a + 1][2 * bq]     = q.z;
                        P[2 * a + 1][2 * bq + 1] = q.w;
                    }
                // Haar butterflies (x2 of true subbands) + dwconv accumulate.
                // 0.5 scale folded into g_wt_s (power-of-2: bit-identical).
                float tc0 = 0.f, tc1 = 0.f, tc2 = 0.f, tc3 = 0.f;
                #pragma unroll
                for (int dy = 0; dy < 3; ++dy) {
                    #pragma unroll
                    for (int dx = 0; dx < 3; ++dx) {
                        const float a  = P[2 * dy][2 * dx];
                        const float b2 = P[2 * dy][2 * dx + 1];
                        const float c2 = P[2 * dy + 1][2 * dx];
                        const float d2 = P[2 * dy + 1][2 * dx + 1];
                        const float s0 = a + b2, s1 = c2 + d2;
                        const float d0 = a - b2, d1 = c2 - d2;
                        const int wo = dy * 3 + dx;
                        tc0 += wb[(c * 4 + 0) * 9 + wo] * (s0 + s1);   // 2*LL
                        tc1 += wb[(c * 4 + 1) * 9 + wo] * (s0 - s1);   // 2*LH
                        tc2 += wb[(c * 4 + 2) * 9 + wo] * (d0 + d1);   // 2*HL
                        tc3 += wb[(c * 4 + 3) * 9 + wo] * (d0 - d1);   // 2*HH
                    }
                }
                const float t0 = tc0 * (0.5f * g_wt_s[br * 20 + c * 4 + 0]);
                const float t1 = tc1 * (0.5f * g_wt_s[br * 20 + c * 4 + 1]);
                const float t2 = tc2 * (0.5f * g_wt_s[br * 20 + c * 4 + 2]);
                const float t3 = tc3 * (0.5f * g_wt_s[br * 20 + c * 4 + 3]);
                const float xt0 = 0.5f * (t0 + t1 + t2 + t3);
                const float xt1 = 0.5f * (t0 + t1 - t2 - t3);
                const float xt2 = 0.5f * (t0 - t1 + t2 - t3);
                const float xt3 = 0.5f * (t0 - t1 - t2 + t3);
                const float* bw = g_base_w + br * 45 + c * 9;
                const float bb2 = g_base_b[br * 5 + c], bs = g_base_s[br * 5 + c];
                #pragma unroll
                for (int p = 0; p < 4; ++p) {
                    const int py = p >> 1, px = p & 1;
                    float acc = 0.f;
                    #pragma unroll
                    for (int dy = 0; dy < 3; ++dy)
                        #pragma unroll
                        for (int dx = 0; dx < 3; ++dx)
                            acc += bw[dy * 3 + dx] * P[1 + py + dy][1 + px + dx];
                    const float xtv = (p == 0) ? xt0 : (p == 1) ? xt1 : (p == 2) ? xt2 : xt3;
                    gi[c][p] = (acc + bb2) * bs + xtv;
                }
            }

            // ---------- 5x5 pointwise + tail accumulation (lw hoisted) ----------
            #pragma unroll
            for (int o = 0; o < 5; ++o) {
                const int cg = br * 5 + o;
                float v[4];
                #pragma unroll
                for (int p = 0; p < 4; ++p) {
                    float vv = 0.f;
                    #pragma unroll
                    for (int c = 0; c < 5; ++c) vv += g_pw_w[br * 25 + o * 5 + c] * gi[c][p];
                    v[p] = vv;
                    S1[p] += vv;
                    S2[p] += vv * vv;
                }
                const float lw = tail_ln_w[cg];
                #pragma unroll
                for (int o8 = 0; o8 < 8; ++o8) {
                    const float w = tail_w[o8 * 20 + cg] * lw;
                    T[0][o8] += w * v[0];
                    T[1][o8] += w * v[1];
                    T[2][o8] += w * v[2];
                    T[3][o8] += w * v[3];
                }
            }
        }
        if (pair == 0) __syncthreads();
    }

    // ---------- Phase 5: tail LN (closed form) + 1x1 + GELU + residual ----------
    float A[8], Bc[8];
    #pragma unroll
    for (int o = 0; o < 8; ++o) {
        A[o]  = ws[WS_AB_OFF + o];
        Bc[o] = ws[WS_AB_OFF + 8 + o];
    }

    #pragma unroll
    for (int py = 0; py < 2; ++py) {
        const int p0 = py * 2, p1 = py * 2 + 1;
        const int gy  = ty0 + 2 * ty + py;
        const int gx0 = tx0 + 2 * tx;
        const float u0    = S1[p0] * 0.05f;
        const float u1    = S1[p1] * 0.05f;
        const float rstd0 = rsqrtf(S2[p0] * 0.05f - u0 * u0 + 1e-6f);
        const float rstd1 = rsqrtf(S2[p1] * 0.05f - u1 * u1 + 1e-6f);

        const int xbase = xlb + gy * HL + gx0;
        float2 xlv[8];
        #pragma unroll
        for (int c = 0; c < 8; ++c) xlv[c] = *(const float2*)&xl[xbase + c * plane];
        const float2 mk = *(const float2*)&mask[mb + gy * HL + gx0];

        #pragma unroll
        for (int o = 0; o < 8; ++o) {
            const float val0 = (T[p0][o] - u0 * A[o]) * rstd0 + Bc[o];
            const float val1 = (T[p1][o] - u1 * A[o]) * rstd1 + Bc[o];
            float r0 = res_b[o] + res_w[o * 9 + 8] * mk.x;
            float r1 = res_b[o] + res_w[o * 9 + 8] * mk.y;
            #pragma unroll
            for (int c = 0; c < 8; ++c) {
                r0 += res_w[o * 9 + c] * xlv[c].x;
                r1 += res_w[o * 9 + c] * xlv[c].y;
            }
            float2 ov;
            ov.x = gelu_fast(val0) + r0;
            ov.y = gelu_fast(val1) + r1;
            *(float2*)&out[xbase + o * plane] = ov;
        }
    }
}

extern "C" void kernel_launch(void* const* d_in, const int* in_sizes, int n_in,
                              void* d_out, int out_size, void* d_ws, size_t ws_size,
                              hipStream_t stream) {
    (void)in_sizes; (void)out_size;
    if (n_in < 19) return;
    const float* xh        = (const float*)d_in[0];
    const float* xl        = (const float*)d_in[1];
    const float* mask      = (const float*)d_in[2];
    const float* pre_w     = (const float*)d_in[3];
    const float* pre_b     = (const float*)d_in[4];
    const float* g_ln_w    = (const float*)d_in[5];
    const float* g_ln_b    = (const float*)d_in[6];
    const float* g_base_w  = (const float*)d_in[7];
    const float* g_base_b  = (const float*)d_in[8];
    const float* g_base_s  = (const float*)d_in[9];
    const float* g_wt_w    = (const float*)d_in[10];
    const float* g_wt_s    = (const float*)d_in[11];
    const float* g_pw_w    = (const float*)d_in[12];
    const float* tail_ln_w = (const float*)d_in[13];
    const float* tail_ln_b = (const float*)d_in[14];
    const float* tail_w    = (const float*)d_in[15];
    const float* tail_b    = (const float*)d_in[16];
    const float* res_w     = (const float*)d_in[17];
    const float* res_b     = (const float*)d_in[18];
    float* outp = (float*)d_out;
    float* ws   = (float*)d_ws;

    if (ws == nullptr || ws_size < WS_NEEDED_BYTES) return;  // harness provides ws

    pre_project_kernel<<<dim3(2048), dim3(256), 0, stream>>>(
        xh, pre_w, pre_b, tail_ln_w, tail_ln_b, tail_w, tail_b, ws);
    uem_pair_kernel<<<dim3(HL / TS, HL / TS, BB), dim3(16, 16, 1), 0, stream>>>(
        xl, mask, g_ln_w, g_ln_b, g_base_w, g_base_b, g_base_s,
        g_wt_w, g_wt_s, g_pw_w, tail_ln_w, tail_w, res_w, res_b, ws, outp);
}

// Round 10
// 287.296 us; speedup vs baseline: 1.6760x; 1.0324x over previous
//
#include <hip/hip_runtime.h>
#include <math.h>

// Problem constants (from setup_inputs)
#define BB   8
#define CXH  16
#define CXL  8
#define HH   256
#define HL   512

// Tiling
#define TS   32              // 512-res tile edge
#define HALO 2
#define GT   (TS + 2*HALO)   // 36 : LN'd tile + halo
#define NPAIR (GT * GT / 2)  // 648 pixel-pair tasks per tile

// Workspace layout (floats):
//  [0, WS_PATCH)        pre-projected xh, branch-pair interleaved
//  +16   A[8], Bc[8]    folded tail affine
//  +160  W2t[cg][o8]    tail_w * tail_ln_w, transposed (cg-major)
//  +720  wbs            g_wt_w * (0.5*g_wt_s)   [br][c][k][9]
//  +180  bws            g_base_w * g_base_s     [br][c][9]
//  +20   bbs            g_base_b * g_base_s     [br][c]
#define WS_PATCH_FLOATS (BB * 4 * HH * HH * 2)     // 4,194,304 floats = 16 MB
#define WS_AB_OFF       WS_PATCH_FLOATS
#define WS_W2T_OFF      (WS_AB_OFF + 16)
#define WS_WBS_OFF      (WS_W2T_OFF + 160)
#define WS_BWS_OFF      (WS_WBS_OFF + 720)
#define WS_BBS_OFF      (WS_BWS_OFF + 180)
#define WS_TOTAL_FLOATS (WS_BBS_OFF + 20)
#define WS_NEEDED_BYTES ((size_t)WS_TOTAL_FLOATS * sizeof(float))

// Branch-free fast GELU (tanh-form); |delta| vs exact ~1e-3 << 0.155 tol.
__device__ __forceinline__ float gelu_fast(float x) {
    const float u = x * (1.595769122f + 0.071354816f * x * x);
    return x * __builtin_amdgcn_rcpf(1.0f + __expf(-u));
}

// Channels-first LN over 5 values (order identical to all prior rounds).
__device__ __forceinline__ void ln5(float* vv, const float* w, const float* bta) {
    const float u = (vv[0] + vv[1] + vv[2] + vv[3] + vv[4]) * 0.2f;
    float var = 0.f;
    #pragma unroll
    for (int c = 0; c < 5; ++c) { const float d = vv[c] - u; var += d * d; }
    var *= 0.2f;
    const float rstd = rsqrtf(var + 1e-6f);
    #pragma unroll
    for (int c = 0; c < 5; ++c) vv[c] = w[c] * ((vv[c] - u) * rstd) + bta[c];
}

// Bilinear lerp of a pair-interleaved (2-channel) corner set.
__device__ __forceinline__ void bil2(const float* __restrict__ wsp, int cbase,
                                     float fx, float fy, float& o0, float& o1) {
    const float2 q00 = *(const float2*)&wsp[cbase];
    const float2 q01 = *(const float2*)&wsp[cbase + 2];
    const float2 q10 = *(const float2*)&wsp[cbase + 2 * HH];
    const float2 q11 = *(const float2*)&wsp[cbase + 2 * HH + 2];
    {
        const float top = q00.x + fx * (q01.x - q00.x);
        const float bot = q10.x + fx * (q11.x - q10.x);
        o0 = top + fy * (bot - top);
    }
    {
        const float top = q00.y + fx * (q01.y - q00.y);
        const float bot = q10.y + fx * (q11.y - q10.y);
        o1 = top + fy * (bot - top);
    }
}

// ---------------- Prepass: 1x1 projection 16->8 + folded weight tables ----------------
__global__ __launch_bounds__(256)
void pre_project_kernel(const float* __restrict__ xh,
                        const float* __restrict__ pre_w,
                        const float* __restrict__ pre_b,
                        const float* __restrict__ g_base_w,
                        const float* __restrict__ g_base_b,
                        const float* __restrict__ g_base_s,
                        const float* __restrict__ g_wt_w,
                        const float* __restrict__ g_wt_s,
                        const float* __restrict__ tail_ln_w,
                        const float* __restrict__ tail_ln_b,
                        const float* __restrict__ tail_w,
                        const float* __restrict__ tail_b,
                        float* __restrict__ ws)
{
    const int gid = blockIdx.x * 256 + threadIdx.x;   // 524288 = 8*256*256
    const int b   = gid >> 16;
    const int px  = gid & 0xFFFF;
    const float* xp = xh + (b * CXH) * (HH * HH) + px;
    float xv[16];
    #pragma unroll
    for (int c = 0; c < 16; ++c) xv[c] = xp[c * HH * HH];
    #pragma unroll
    for (int br = 0; br < 4; ++br) {
        float a0 = pre_b[2 * br], a1 = pre_b[2 * br + 1];
        #pragma unroll
        for (int c = 0; c < 16; ++c) {
            a0 += pre_w[(2 * br) * 16 + c] * xv[c];
            a1 += pre_w[(2 * br + 1) * 16 + c] * xv[c];
        }
        float2 r; r.x = a0; r.y = a1;
        *(float2*)&ws[((b * 4 + br) * (HH * HH) + px) * 2] = r;
    }
    // Folded weight tables (tiny, one thread each).
    if (gid < 8) {
        const int o = gid;
        float a = 0.f, bb = tail_b[o];
        for (int cg = 0; cg < 20; ++cg) {
            a  += tail_w[o * 20 + cg] * tail_ln_w[cg];
            bb += tail_w[o * 20 + cg] * tail_ln_b[cg];
        }
        ws[WS_AB_OFF + o]     = a;
        ws[WS_AB_OFF + 8 + o] = bb;
    } else if (gid < 8 + 160) {
        const int i = gid - 8;                 // cg*8 + o8
        const int cg = i / 8, o8 = i % 8;
        ws[WS_W2T_OFF + i] = tail_w[o8 * 20 + cg] * tail_ln_w[cg];
    } else if (gid < 8 + 160 + 720) {
        const int i = gid - 168;               // ((br*5+c)*4+k)*9 + wo
        const int wo = i % 9;
        const int rest = i / 9;
        const int k = rest % 4;
        const int bc = rest / 4;
        const int br = bc / 5, c = bc % 5;
        ws[WS_WBS_OFF + i] =
            g_wt_w[br * 180 + (c * 4 + k) * 9 + wo] * (0.5f * g_wt_s[br * 20 + c * 4 + k]);
    } else if (gid < 8 + 160 + 720 + 180) {
        const int i = gid - 888;               // (br*5+c)*9 + wo
        const int wo = i % 9;
        const int bc = i / 9;
        const int br = bc / 5, c = bc % 5;
        ws[WS_BWS_OFF + i] = g_base_w[br * 45 + c * 9 + wo] * g_base_s[bc];
    } else if (gid < 8 + 160 + 720 + 180 + 20) {
        const int i = gid - 1068;              // br*5+c
        ws[WS_BBS_OFF + i] = g_base_b[i] * g_base_s[i];
    }
}

// ---------------- Phase-1 helper: pixel-PAIR LN build (both branches) ----------------
// EDGE=false (interior blocks): bounds check and clamps provably unnecessary.
// Bounds are pair-uniform: gx0 is always even, OOB only at gx0 = -2 or 512.
template <bool EDGE>
__device__ __forceinline__ void build_pair_lds(
    float (&s_q)[2][5][18][18][4],
    int tid, int ty0, int tx0, int mb, int xlb, int pair,
    const float* __restrict__ xl, const float* __restrict__ mask,
    const float* __restrict__ g_ln_w, const float* __restrict__ g_ln_b,
    const float* __restrict__ wsp0, const float* __restrict__ wsp1)
{
    const float SC = (float)(255.0 / 511.0);
    const int plane = HL * HL;
    const float* gwA = g_ln_w + (2 * pair) * 5;
    const float* gbA = g_ln_b + (2 * pair) * 5;
    const float* gwB = g_ln_w + (2 * pair + 1) * 5;
    const float* gbB = g_ln_b + (2 * pair + 1) * 5;

    int r = tid / 18, m = tid % 18;
    for (int task = tid; task < NPAIR; task += 256) {
        const int gy  = ty0 - HALO + r;
        const int gx0 = tx0 - HALO + 2 * m;
        float a0[5] = {0,0,0,0,0}, a1[5] = {0,0,0,0,0};
        float b0[5] = {0,0,0,0,0}, b1[5] = {0,0,0,0,0};
        bool ok = true;
        if (EDGE) ok = (gy >= 0) && (gy < HL) && (gx0 >= 0) && (gx0 < HL);
        if (ok) {
            const float cy = (float)gy * SC;
            int iy0 = (int)cy;
            if (EDGE) iy0 = min(iy0, HH - 2);
            const float fy = cy - (float)iy0;
            const float cx0 = (float)gx0 * SC;
            int ix00 = (int)cx0;
            if (EDGE) ix00 = min(ix00, HH - 2);
            const float fx0 = cx0 - (float)ix00;
            const float cx1 = (float)(gx0 + 1) * SC;
            int ix01 = (int)cx1;
            if (EDGE) ix01 = min(ix01, HH - 2);
            const float fx1 = cx1 - (float)ix01;
            const int c0 = (iy0 * HH + ix00) * 2;
            const int c1 = (iy0 * HH + ix01) * 2;
            const int pix = gy * HL + gx0;
            const float2 mk = *(const float2*)&mask[mb + pix];

            bil2(wsp0, c0, fx0, fy, a0[0], a0[1]);
            bil2(wsp0, c1, fx1, fy, a1[0], a1[1]);
            bil2(wsp1, c0, fx0, fy, b0[0], b0[1]);
            bil2(wsp1, c1, fx1, fy, b1[0], b1[1]);

            const float2 x0 = *(const float2*)&xl[xlb + (4 * pair + 0) * plane + pix];
            const float2 x1 = *(const float2*)&xl[xlb + (4 * pair + 1) * plane + pix];
            const float2 x2 = *(const float2*)&xl[xlb + (4 * pair + 2) * plane + pix];
            const float2 x3 = *(const float2*)&xl[xlb + (4 * pair + 3) * plane + pix];
            a0[2] = x0.x; a1[2] = x0.y; a0[3] = x1.x; a1[3] = x1.y;
            a0[4] = mk.x; a1[4] = mk.y;
            b0[2] = x2.x; b1[2] = x2.y; b0[3] = x3.x; b1[3] = x3.y;
            b0[4] = mk.x; b1[4] = mk.y;

            ln5(a0, gwA, gbA); ln5(a1, gwA, gbA);
            ln5(b0, gwB, gbB); ln5(b1, gwB, gbB);
        }
        const int qy = r >> 1, sub0 = (r & 1) * 2;
        #pragma unroll
        for (int c = 0; c < 5; ++c) {
            float2 t; t.x = a0[c]; t.y = a1[c];
            *(float2*)&s_q[0][c][qy][m][sub0] = t;
        }
        #pragma unroll
        for (int c = 0; c < 5; ++c) {
            float2 t; t.x = b0[c]; t.y = b1[c];
            *(float2*)&s_q[1][c][qy][m][sub0] = t;
        }
        // task += 256  ==  r += 14, m += 4  (256 = 14*18 + 4), single wrap
        m += 4; r += 14;
        if (m >= 18) { m -= 18; r += 1; }
    }
}

// ---------------- Main fused kernel: branch-PAIR loop (R9 structure) ----------------
__global__ __launch_bounds__(256, 3)
void uem_pair_kernel(const float* __restrict__ xl,
                     const float* __restrict__ mask,
                     const float* __restrict__ g_ln_w,
                     const float* __restrict__ g_ln_b,
                     const float* __restrict__ g_pw_w,
                     const float* __restrict__ res_w,
                     const float* __restrict__ res_b,
                     const float* __restrict__ ws,
                     float* __restrict__ out)
{
    __shared__ __align__(16) float s_q[2][5][18][18][4];   // 51840 B

    const int b   = blockIdx.z;
    const int ty0 = blockIdx.y * TS;
    const int tx0 = blockIdx.x * TS;
    const int tx  = threadIdx.x, ty = threadIdx.y;
    const int tid = ty * 16 + tx;
    const bool edge = (blockIdx.x == 0) || (blockIdx.x == gridDim.x - 1) ||
                      (blockIdx.y == 0) || (blockIdx.y == gridDim.y - 1);

    const int plane = HL * HL;
    const int mb  = b * plane;
    const int xlb = (b * CXL) * plane;

    float S1[4] = {0.f, 0.f, 0.f, 0.f};
    float S2[4] = {0.f, 0.f, 0.f, 0.f};
    float T[4][8];
    #pragma unroll
    for (int p = 0; p < 4; ++p)
        #pragma unroll
        for (int o = 0; o < 8; ++o) T[p][o] = 0.f;

    for (int pair = 0; pair < 2; ++pair) {
        // ---------- Phase 1: LN'd inputs for BOTH branches of the pair ----------
        const float* wsp0 = ws + ((size_t)(b * 4 + 2 * pair)     * (HH * HH)) * 2;
        const float* wsp1 = ws + ((size_t)(b * 4 + 2 * pair + 1) * (HH * HH)) * 2;
        if (edge)
            build_pair_lds<true >(s_q, tid, ty0, tx0, mb, xlb, pair,
                                  xl, mask, g_ln_w, g_ln_b, wsp0, wsp1);
        else
            build_pair_lds<false>(s_q, tid, ty0, tx0, mb, xlb, pair,
                                  xl, mask, g_ln_w, g_ln_b, wsp0, wsp1);
        __syncthreads();

        // ---------- Conv block for each branch of the pair ----------
        for (int s = 0; s < 2; ++s) {
            const int br = 2 * pair + s;
            const float* wbs = ws + WS_WBS_OFF + (size_t)(br * 5) * 36;
            const float* bws = ws + WS_BWS_OFF + (size_t)(br * 5) * 9;
            const float* bbs = ws + WS_BBS_OFF + br * 5;
            float gi[5][4];
            #pragma unroll
            for (int c = 0; c < 5; ++c) {
                // 6x6 patch via 9 aligned b128 quad reads
                float P[6][6];
                #pragma unroll
                for (int a = 0; a < 3; ++a)
                    #pragma unroll
                    for (int bq = 0; bq < 3; ++bq) {
                        const float4 q = *(const float4*)&s_q[s][c][ty + a][tx + bq][0];
                        P[2 * a][2 * bq]         = q.x;
                        P[2 * a][2 * bq + 1]     = q.y;
                        P[2 * a + 1][2 * bq]     = q.z;
                        P[2 * a + 1][2 * bq + 1] = q.w;
                    }
                // Haar butterflies + dwconv with PRE-SCALED weights (wbs):
                // t_k = sum( wbs_k * butterfly_k ), wbs = wt_w * 0.5 * wt_s.
                const float* wc = wbs + c * 36;
                float t0 = 0.f, t1 = 0.f, t2 = 0.f, t3 = 0.f;
                #pragma unroll
                for (int dy = 0; dy < 3; ++dy) {
                    #pragma unroll
                    for (int dx = 0; dx < 3; ++dx) {
                        const float a  = P[2 * dy][2 * dx];
                        const float b2 = P[2 * dy][2 * dx + 1];
                        const float c2 = P[2 * dy + 1][2 * dx];
                        const float d2 = P[2 * dy + 1][2 * dx + 1];
                        const float s0 = a + b2, s1 = c2 + d2;
                        const float d0 = a - b2, d1 = c2 - d2;
                        const int wo = dy * 3 + dx;
                        t0 += wc[wo]      * (s0 + s1);   // LL
                        t1 += wc[9 + wo]  * (s0 - s1);   // LH
                        t2 += wc[18 + wo] * (d0 + d1);   // HL
                        t3 += wc[27 + wo] * (d0 - d1);   // HH
                    }
                }
                const float xt0 = 0.5f * (t0 + t1 + t2 + t3);
                const float xt1 = 0.5f * (t0 + t1 - t2 - t3);
                const float xt2 = 0.5f * (t0 - t1 + t2 - t3);
                const float xt3 = 0.5f * (t0 - t1 - t2 + t3);
                // Base 3x3 dwconv with PRE-SCALED weights, bias-initialized acc.
                const float* bwc = bws + c * 9;
                const float bc = bbs[c];
                #pragma unroll
                for (int p = 0; p < 4; ++p) {
                    const int py = p >> 1, px = p & 1;
                    float acc = bc;
                    #pragma unroll
                    for (int dy = 0; dy < 3; ++dy)
                        #pragma unroll
                        for (int dx = 0; dx < 3; ++dx)
                            acc += bwc[dy * 3 + dx] * P[1 + py + dy][1 + px + dx];
                    const float xtv = (p == 0) ? xt0 : (p == 1) ? xt1 : (p == 2) ? xt2 : xt3;
                    gi[c][p] = acc + xtv;
                }
            }

            // ---------- 5x5 pointwise + tail accumulation (W2t pre-folded) ----------
            #pragma unroll
            for (int o = 0; o < 5; ++o) {
                const int cg = br * 5 + o;
                float v[4];
                #pragma unroll
                for (int p = 0; p < 4; ++p) {
                    float vv = 0.f;
                    #pragma unroll
                    for (int c = 0; c < 5; ++c) vv += g_pw_w[br * 25 + o * 5 + c] * gi[c][p];
                    v[p] = vv;
                    S1[p] += vv;
                    S2[p] += vv * vv;
                }
                const float* w2 = ws + WS_W2T_OFF + cg * 8;   // 8 consecutive floats
                #pragma unroll
                for (int o8 = 0; o8 < 8; ++o8) {
                    const float w = w2[o8];
                    T[0][o8] += w * v[0];
                    T[1][o8] += w * v[1];
                    T[2][o8] += w * v[2];
                    T[3][o8] += w * v[3];
                }
            }
        }
        if (pair == 0) __syncthreads();
    }

    // ---------- Phase 5: tail LN (closed form) + 1x1 + GELU + residual ----------
    float A[8], Bc[8];
    {
        const float4 a0 = *(const float4*)&ws[WS_AB_OFF];
        const float4 a1 = *(const float4*)&ws[WS_AB_OFF + 4];
        const float4 b0 = *(const float4*)&ws[WS_AB_OFF + 8];
        const float4 b1 = *(const float4*)&ws[WS_AB_OFF + 12];
        A[0]=a0.x; A[1]=a0.y; A[2]=a0.z; A[3]=a0.w;
        A[4]=a1.x; A[5]=a1.y; A[6]=a1.z; A[7]=a1.w;
        Bc[0]=b0.x; Bc[1]=b0.y; Bc[2]=b0.z; Bc[3]=b0.w;
        Bc[4]=b1.x; Bc[5]=b1.y; Bc[6]=b1.z; Bc[7]=b1.w;
    }

    #pragma unroll
    for (int py = 0; py < 2; ++py) {
        const int p0 = py * 2, p1 = py * 2 + 1;
        const int gy  = ty0 + 2 * ty + py;
        const int gx0 = tx0 + 2 * tx;
        const float u0    = S1[p0] * 0.05f;
        const float u1    = S1[p1] * 0.05f;
        const float rstd0 = rsqrtf(S2[p0] * 0.05f - u0 * u0 + 1e-6f);
        const float rstd1 = rsqrtf(S2[p1] * 0.05f - u1 * u1 + 1e-6f);

        const int xbase = xlb + gy * HL + gx0;
        float2 xlv[8];
        #pragma unroll
        for (int c = 0; c < 8; ++c) xlv[c] = *(const float2*)&xl[xbase + c * plane];
        const float2 mk = *(const float2*)&mask[mb + gy * HL + gx0];

        #pragma unroll
        for (int o = 0; o < 8; ++o) {
            const float val0 = (T[p0][o] - u0 * A[o]) * rstd0 + Bc[o];
            const float val1 = (T[p1][o] - u1 * A[o]) * rstd1 + Bc[o];
            float r0 = res_b[o] + res_w[o * 9 + 8] * mk.x;
            float r1 = res_b[o] + res_w[o * 9 + 8] * mk.y;
            #pragma unroll
            for (int c = 0; c < 8; ++c) {
                r0 += res_w[o * 9 + c] * xlv[c].x;
                r1 += res_w[o * 9 + c] * xlv[c].y;
            }
            float2 ov;
            ov.x = gelu_fast(val0) + r0;
            ov.y = gelu_fast(val1) + r1;
            *(float2*)&out[xbase + o * plane] = ov;
        }
    }
}

extern "C" void kernel_launch(void* const* d_in, const int* in_sizes, int n_in,
                              void* d_out, int out_size, void* d_ws, size_t ws_size,
                              hipStream_t stream) {
    (void)in_sizes; (void)out_size;
    if (n_in < 19) return;
    const float* xh        = (const float*)d_in[0];
    const float* xl        = (const float*)d_in[1];
    const float* mask      = (const float*)d_in[2];
    const float* pre_w     = (const float*)d_in[3];
    const float* pre_b     = (const float*)d_in[4];
    const float* g_ln_w    = (const float*)d_in[5];
    const float* g_ln_b    = (const float*)d_in[6];
    const float* g_base_w  = (const float*)d_in[7];
    const float* g_base_b  = (const float*)d_in[8];
    const float* g_base_s  = (const float*)d_in[9];
    const float* g_wt_w    = (const float*)d_in[10];
    const float* g_wt_s    = (const float*)d_in[11];
    const float* g_pw_w    = (const float*)d_in[12];
    const float* tail_ln_w = (const float*)d_in[13];
    const float* tail_ln_b = (const float*)d_in[14];
    const float* tail_w    = (const float*)d_in[15];
    const float* tail_b    = (const float*)d_in[16];
    const float* res_w     = (const float*)d_in[17];
    const float* res_b     = (const float*)d_in[18];
    float* outp = (float*)d_out;
    float* ws   = (float*)d_ws;

    if (ws == nullptr || ws_size < WS_NEEDED_BYTES) return;  // harness provides ws

    pre_project_kernel<<<dim3(2048), dim3(256), 0, stream>>>(
        xh, pre_w, pre_b, g_base_w, g_base_b, g_base_s, g_wt_w, g_wt_s,
        tail_ln_w, tail_ln_b, tail_w, tail_b, ws);
    uem_pair_kernel<<<dim3(HL / TS, HL / TS, BB), dim3(16, 16, 1), 0, stream>>>(
        xl, mask, g_ln_w, g_ln_b, g_pw_w, res_w, res_b, ws, outp);
}